// Round 16
// baseline (76.341 us; speedup 1.0000x reference)
//
#include <hip/hip_runtime.h>
#include <hip/hip_bf16.h>

#define HW   8192
#define W0   128
#define H0   64
#define CDIM 256

typedef int int4v __attribute__((ext_vector_type(4)));

__device__ __forceinline__ int4v mfma_i8_16x16x64(int4v a, int4v b, int4v c) {
    asm volatile("v_mfma_i32_16x16x64_i8 %0, %1, %2, %0"
                 : "+v"(c) : "v"(a), "v"(b));
    return c;
}

// ---------- K1: transpose+quantize fmap1 -> q1[8192][256] int8, s1[8192] ----------
__global__ __launch_bounds__(256) void k_q_f1(const float* __restrict__ in,
                                              signed char* __restrict__ q1,
                                              float* __restrict__ s1) {
    __shared__ float lds[32][257];
    __shared__ float sInv[32];
    __shared__ float sSc[32];
    const int m0 = blockIdx.x * 32;
    const int tc = threadIdx.x & 31;
    const int tr = threadIdx.x >> 5;
    #pragma unroll 4
    for (int r = 0; r < 32; ++r) {
        const int c = r * 8 + tr;
        lds[tc][c] = in[(size_t)c * HW + m0 + tc];
    }
    __syncthreads();
    const int row = threadIdx.x >> 3, t8 = threadIdx.x & 7;
    float am = 0.f;
    #pragma unroll 8
    for (int k = 0; k < 32; ++k) am = fmaxf(am, fabsf(lds[row][t8 * 32 + k]));
    am = fmaxf(am, __shfl_xor(am, 1));
    am = fmaxf(am, __shfl_xor(am, 2));
    am = fmaxf(am, __shfl_xor(am, 4));
    if (t8 == 0) {
        sInv[row] = am > 0.f ? 127.f / am : 0.f;
        sSc[row]  = (am / 127.f) * 0.0625f;
    }
    __syncthreads();
    const int c = threadIdx.x;
    #pragma unroll 4
    for (int ml = 0; ml < 32; ++ml) {
        q1[(size_t)(m0 + ml) * CDIM + c] =
            (signed char)__float2int_rn(lds[ml][c] * sInv[ml]);
    }
    if (threadIdx.x < 32) s1[m0 + threadIdx.x] = sSc[threadIdx.x];
}

// ---------- K2: fused transpose + level-0 quant: fmap2 -> p0 f16, q-level0 int8, s2 ----------
__global__ __launch_bounds__(256) void k_tq_f2(const float* __restrict__ in,
                                               _Float16* __restrict__ p0,
                                               signed char* __restrict__ q0,
                                               float* __restrict__ s2) {
    __shared__ float lds[32][257];
    __shared__ float sInv[32];
    __shared__ float sSc[32];
    const int m0 = blockIdx.x * 32;
    const int tc = threadIdx.x & 31;
    const int tr = threadIdx.x >> 5;
    #pragma unroll 4
    for (int r = 0; r < 32; ++r) {
        const int c = r * 8 + tr;
        lds[tc][c] = in[(size_t)c * HW + m0 + tc];
    }
    __syncthreads();
    const int row = threadIdx.x >> 3, t8 = threadIdx.x & 7;
    float am = 0.f;
    #pragma unroll 8
    for (int k = 0; k < 32; ++k) am = fmaxf(am, fabsf(lds[row][t8 * 32 + k]));
    am = fmaxf(am, __shfl_xor(am, 1));
    am = fmaxf(am, __shfl_xor(am, 2));
    am = fmaxf(am, __shfl_xor(am, 4));
    if (t8 == 0) {
        sInv[row] = am > 0.f ? 127.f / am : 0.f;
        sSc[row]  = am / 127.f;
    }
    __syncthreads();
    const int c = threadIdx.x;
    #pragma unroll 4
    for (int ml = 0; ml < 32; ++ml) {
        const float v = lds[ml][c];
        p0[(size_t)(m0 + ml) * CDIM + c] = (_Float16)v;
        q0[(size_t)(m0 + ml) * CDIM + c] = (signed char)__float2int_rn(v * sInv[ml]);
    }
    if (threadIdx.x < 32) s2[m0 + threadIdx.x] = sSc[threadIdx.x];
}

// ---------- K3: fused pool(1,2,3) + quant, all from p0 ----------
__global__ __launch_bounds__(256) void k_pq(const _Float16* __restrict__ p0,
                                            signed char* __restrict__ pyrQ,
                                            float* __restrict__ s2) {
    const int b = blockIdx.x;
    int w, t;
    if (b < 2048)      { w = 1; t = b; }
    else if (b < 2560) { w = 2; t = b - 2048; }
    else               { w = 3; t = b - 2560; }
    const int Wl = W0 >> w;
    const int f  = 1 << w;
    const int X  = t & (Wl - 1);
    const int Y  = t / Wl;
    const int c  = threadIdx.x;

    float s = 0.f;
    for (int dy = 0; dy < f; ++dy) {
        const size_t rb = ((size_t)(Y * f + dy) * W0 + X * f) * CDIM + c;
        for (int dx = 0; dx < f; ++dx) s += (float)p0[rb + (size_t)dx * CDIM];
    }
    const float v = s / (float)(f * f);

    __shared__ float wmax[4];
    float am = fabsf(v);
    #pragma unroll
    for (int d = 1; d < 64; d <<= 1) am = fmaxf(am, __shfl_xor(am, d));
    if ((threadIdx.x & 63) == 0) wmax[threadIdx.x >> 6] = am;
    __syncthreads();
    am = fmaxf(fmaxf(wmax[0], wmax[1]), fmaxf(wmax[2], wmax[3]));
    const float inv = am > 0.f ? 127.f / am : 0.f;

    const int texoff = (w == 1) ? 8192 : (w == 2) ? 10240 : 10752;
    pyrQ[((size_t)(texoff + t) << 8) + c] = (signed char)__float2int_rn(v * inv);
    if (threadIdx.x == 0) s2[texoff + t] = am / 127.f;
}

// ---------- K4 (MFMA via inline asm): block-bbox GEMM + scatter, 16 px/block ----------
// 512 blocks x 1024 threads (16 waves), 16 pixels/block (R14 shape; 2 blk/CU).
// Per level: block-uniform bbox; waves grab (row, 16-texel chunk) items; each
// item = [16px x 256ch] x [256ch x 16tex] via 4x v_mfma_i32_16x16x64_i8.
// D (col=lane&15=texel, row=(lane>>4)*4+reg=pixel) scaled by s2, scattered
// into sG with bounds checks.
__global__ __launch_bounds__(1024, 4) void k_sample_mfma(
        const signed char* __restrict__ q1, const float* __restrict__ s1,
        const signed char* __restrict__ pyrQ, const float* __restrict__ s2,
        const float* __restrict__ coords, float* __restrict__ out) {
    const int tid  = threadIdx.x;
    const int wv   = tid >> 6;
    const int lane = tid & 63;
    const int m0   = blockIdx.x * 16;

    __shared__ float sG[16][4][105];
    __shared__ float sF[16][4][2];
    __shared__ float sS[16];
    __shared__ int   sX0[4][16];
    __shared__ int   sY0[4][16];

    {
        float* gz = &sG[0][0][0];
        for (int k = tid; k < 16 * 4 * 105; k += 1024) gz[k] = 0.f;
    }
    if (tid < 16) {
        sS[tid] = s1[m0 + tid];
        const float cx = coords[m0 + tid];
        const float cy = coords[HW + m0 + tid];
        #pragma unroll
        for (int w = 0; w < 4; ++w) {
            const float scale = 1.0f / (float)(1 << w);
            const float xs = cx * scale, ys = cy * scale;
            const float X0f = floorf(xs), Y0f = floorf(ys);
            sX0[w][tid] = (int)X0f;
            sY0[w][tid] = (int)Y0f;
            sF[tid][w][0] = xs - X0f;
            sF[tid][w][1] = ys - Y0f;
        }
    }
    __syncthreads();

    // A fragments: lane holds pixel (lane&15), channels (lane>>4)*16 + 64*kk
    const signed char* ap = q1 + (size_t)(m0 + (lane & 15)) * CDIM + ((lane >> 4) << 4);
    const int4v A0 = *reinterpret_cast<const int4v*>(ap);
    const int4v A1 = *reinterpret_cast<const int4v*>(ap + 64);
    const int4v A2 = *reinterpret_cast<const int4v*>(ap + 128);
    const int4v A3 = *reinterpret_cast<const int4v*>(ap + 192);

    #pragma unroll
    for (int w = 0; w < 4; ++w) {
        const int Wl = W0 >> w;
        const int Hl = H0 >> w;
        const int texoff = (w == 0) ? 0 : (w == 1) ? 8192 : (w == 2) ? 10240 : 10752;
        const signed char* lvl = pyrQ + ((size_t)texoff << 8);
        const float* s2l = s2 + texoff;

        int minX = 1 << 30, maxX = -(1 << 30), minY = 1 << 30, maxY = -(1 << 30);
        #pragma unroll
        for (int p = 0; p < 16; ++p) {
            const int x0 = sX0[w][p], y0 = sY0[w][p];
            minX = min(minX, x0); maxX = max(maxX, x0);
            minY = min(minY, y0); maxY = max(maxY, y0);
        }
        const int xlo = max(minX - 4, 0), xhi = min(maxX + 5, Wl - 1);
        const int ylo = max(minY - 4, 0), yhi = min(maxY + 5, Hl - 1);
        if (xlo > xhi || ylo > yhi) continue;
        const int span  = xhi - xlo + 1;
        const int cpr   = (span + 15) >> 4;
        const int items = (yhi - ylo + 1) * cpr;
        const unsigned mgc = (16777215u / (unsigned)cpr) + 1u;  // ceil(2^24/cpr)

        for (int it = wv; it < items; it += 16) {
            const int rowi = (int)(((unsigned long long)(unsigned)it * mgc) >> 24);
            const int gy   = ylo + rowi;
            const int t0   = xlo + (it - rowi * cpr) * 16;
            const int gxl  = t0 + (lane & 15);
            const int gxc  = min(gxl, xhi);
            const signed char* bp = lvl + (((size_t)(gy * Wl + gxc)) << 8) + ((lane >> 4) << 4);
            int4v acc = {0, 0, 0, 0};
            acc = mfma_i8_16x16x64(A0, *reinterpret_cast<const int4v*>(bp),       acc);
            acc = mfma_i8_16x16x64(A1, *reinterpret_cast<const int4v*>(bp + 64),  acc);
            acc = mfma_i8_16x16x64(A2, *reinterpret_cast<const int4v*>(bp + 128), acc);
            acc = mfma_i8_16x16x64(A3, *reinterpret_cast<const int4v*>(bp + 192), acc);
            const float s2v = s2l[gy * Wl + gxc];
            const bool xok = (gxl <= xhi);
            #pragma unroll
            for (int r = 0; r < 4; ++r) {
                const int px = ((lane >> 4) << 2) + r;
                const int j = gy - sY0[w][px] + 4;
                const int i = gxl - sX0[w][px] + 4;
                if (xok && (unsigned)j < 10u && (unsigned)i < 10u)
                    sG[px][w][j * 10 + i] = (float)acc[r] * s2v;
            }
        }
    }
    __syncthreads();

    const int cpx = tid & 15;
    const float s1v = sS[cpx];
    for (int o = tid >> 4; o < 324; o += 64) {
        const int lev = (o * 811) >> 16;
        const int k   = o - lev * 81;
        const int a   = (k * 57) >> 9;
        const int bb  = k - a * 9;
        const float fx = sF[cpx][lev][0], fy = sF[cpx][lev][1];
        const float wx0 = 1.0f - fx, wy0 = 1.0f - fy;
        const float* G = sG[cpx][lev];
        const float v = wy0 * (wx0 * G[bb * 10 + a]       + fx * G[bb * 10 + a + 1])
                      + fy  * (wx0 * G[(bb + 1) * 10 + a] + fx * G[(bb + 1) * 10 + a + 1]);
        out[(size_t)o * HW + m0 + cpx] = v * s1v;
    }
}

extern "C" void kernel_launch(void* const* d_in, const int* in_sizes, int n_in,
                              void* d_out, int out_size, void* d_ws, size_t ws_size,
                              hipStream_t stream) {
    const float* fmap1  = (const float*)d_in[0];
    const float* fmap2  = (const float*)d_in[1];
    const float* coords = (const float*)d_in[2];
    float* out = (float*)d_out;

    char* ws = (char*)d_ws;
    signed char* q1  = (signed char*)ws;                    // 2,097,152
    float* s1        = (float*)(ws + 2097152);              // 32,768
    float* s2        = (float*)(ws + 2129920);              // 43,520
    signed char* pyrQ = (signed char*)(ws + 2176000);       // 2,785,280
    _Float16* p0     = (_Float16*)(ws + 4961280);           // 4,194,304 (level0 f16)

    k_tq_f2<<<HW / 32, 256, 0, stream>>>(fmap2, p0, pyrQ, s2);
    k_pq<<<2688, 256, 0, stream>>>(p0, pyrQ, s2);
    k_q_f1<<<HW / 32, 256, 0, stream>>>(fmap1, q1, s1);
    k_sample_mfma<<<HW / 16, 1024, 0, stream>>>(q1, s1, pyrQ, s2, coords, out);
}

// Round 17
// 54.743 us; speedup vs baseline: 1.3945x; 1.3945x over previous
//
#include <hip/hip_runtime.h>
#include <hip/hip_bf16.h>

#define HW   8192
#define W0   128
#define H0   64
#define CDIM 256

typedef int int4v __attribute__((ext_vector_type(4)));

__device__ __forceinline__ int4v mfma_i8_16x16x64(int4v a, int4v b, int4v c) {
    asm volatile("v_mfma_i32_16x16x64_i8 %0, %1, %2, %0"
                 : "+v"(c) : "v"(a), "v"(b));
    return c;
}

// ---------- K1: fused transpose + level-0 quant: fmap2 -> p0 f16, q-level0 int8, s2 ----------
__global__ __launch_bounds__(256) void k_tq_f2(const float* __restrict__ in,
                                               _Float16* __restrict__ p0,
                                               signed char* __restrict__ q0,
                                               float* __restrict__ s2) {
    __shared__ float lds[32][257];
    __shared__ float sInv[32];
    __shared__ float sSc[32];
    const int m0 = blockIdx.x * 32;
    const int tc = threadIdx.x & 31;
    const int tr = threadIdx.x >> 5;
    #pragma unroll 4
    for (int r = 0; r < 32; ++r) {
        const int c = r * 8 + tr;
        lds[tc][c] = in[(size_t)c * HW + m0 + tc];
    }
    __syncthreads();
    const int row = threadIdx.x >> 3, t8 = threadIdx.x & 7;
    float am = 0.f;
    #pragma unroll 8
    for (int k = 0; k < 32; ++k) am = fmaxf(am, fabsf(lds[row][t8 * 32 + k]));
    am = fmaxf(am, __shfl_xor(am, 1));
    am = fmaxf(am, __shfl_xor(am, 2));
    am = fmaxf(am, __shfl_xor(am, 4));
    if (t8 == 0) {
        sInv[row] = am > 0.f ? 127.f / am : 0.f;
        sSc[row]  = am / 127.f;
    }
    __syncthreads();
    const int c = threadIdx.x;
    #pragma unroll 4
    for (int ml = 0; ml < 32; ++ml) {
        const float v = lds[ml][c];
        p0[(size_t)(m0 + ml) * CDIM + c] = (_Float16)v;
        q0[(size_t)(m0 + ml) * CDIM + c] = (signed char)__float2int_rn(v * sInv[ml]);
    }
    if (threadIdx.x < 32) s2[m0 + threadIdx.x] = sSc[threadIdx.x];
}

// ---------- K2: pool-from-previous (4 taps) + fused quantize ----------
// One block per output texel; thread = channel. writeF: also emit f16 (levels 1,2).
__global__ __launch_bounds__(256) void k_pool_q(const _Float16* __restrict__ in,
                                                _Float16* __restrict__ outF,
                                                signed char* __restrict__ pyrQ,
                                                float* __restrict__ s2,
                                                int Wout, int Win, int texoff,
                                                int writeF) {
    const int b = blockIdx.x;
    const int X = b % Wout;
    const int Y = b / Wout;
    const int c = threadIdx.x;
    const size_t base = ((size_t)(2 * Y) * Win + 2 * X) * CDIM + c;
    const size_t rows = (size_t)Win * CDIM;
    const float v = 0.25f * ((float)in[base] + (float)in[base + CDIM] +
                             (float)in[base + rows] + (float)in[base + rows + CDIM]);
    if (writeF) outF[(size_t)b * CDIM + c] = (_Float16)v;

    __shared__ float wmax[4];
    float am = fabsf(v);
    #pragma unroll
    for (int d = 1; d < 64; d <<= 1) am = fmaxf(am, __shfl_xor(am, d));
    if ((threadIdx.x & 63) == 0) wmax[threadIdx.x >> 6] = am;
    __syncthreads();
    am = fmaxf(fmaxf(wmax[0], wmax[1]), fmaxf(wmax[2], wmax[3]));
    const float inv = am > 0.f ? 127.f / am : 0.f;
    pyrQ[((size_t)(texoff + b) << 8) + c] = (signed char)__float2int_rn(v * inv);
    if (threadIdx.x == 0) s2[texoff + b] = am / 127.f;
}

// ---------- K3 (MFMA via inline asm): block-bbox GEMM + scatter, 16 px/block ----------
// 512 blocks x 1024 threads (16 waves). Prologue quantizes this block's 16
// fmap1 pixels in-LDS (eliminates the separate k_q_f1 kernel + q1 buffer).
// Core loop identical to R14 (+magic divide).
__global__ __launch_bounds__(1024, 4) void k_sample_mfma(
        const float* __restrict__ fmap1,
        const signed char* __restrict__ pyrQ, const float* __restrict__ s2,
        const float* __restrict__ coords, float* __restrict__ out) {
    const int tid  = threadIdx.x;
    const int wv   = tid >> 6;
    const int lane = tid & 63;
    const int m0   = blockIdx.x * 16;

    __shared__ float sG[16][4][105];
    __shared__ float sF1[16][260];       // f32 f1 staging (pad: 2-way conflicts only)
    __shared__ unsigned int sQ1[16][68]; // packed int8, 4 ch/u32 (pad 68)
    __shared__ float sF[16][4][2];
    __shared__ float sS[16];
    __shared__ int   sX0[4][16];
    __shared__ int   sY0[4][16];

    {
        float* gz = &sG[0][0][0];
        for (int k = tid; k < 16 * 4 * 105; k += 1024) gz[k] = 0.f;
    }
    // stage fmap1 [256][8192] -> sF1[px][c]: thread t loads c=(t>>4)+64r, px=t&15
    {
        const int px = tid & 15;
        const int cb = tid >> 4;
        #pragma unroll
        for (int r = 0; r < 4; ++r) {
            const int c = cb + 64 * r;
            sF1[px][c] = fmap1[(size_t)c * HW + m0 + px];
        }
    }
    if (tid < 16) {
        const float cx = coords[m0 + tid];
        const float cy = coords[HW + m0 + tid];
        #pragma unroll
        for (int w = 0; w < 4; ++w) {
            const float scale = 1.0f / (float)(1 << w);
            const float xs = cx * scale, ys = cy * scale;
            const float X0f = floorf(xs), Y0f = floorf(ys);
            sX0[w][tid] = (int)X0f;
            sY0[w][tid] = (int)Y0f;
            sF[tid][w][0] = xs - X0f;
            sF[tid][w][1] = ys - Y0f;
        }
    }
    __syncthreads();

    // wave wv quantizes pixel wv: lane handles ch 4*lane..4*lane+3
    {
        const float* row = sF1[wv];
        const float v0 = row[4 * lane], v1 = row[4 * lane + 1];
        const float v2 = row[4 * lane + 2], v3 = row[4 * lane + 3];
        float am = fmaxf(fmaxf(fabsf(v0), fabsf(v1)), fmaxf(fabsf(v2), fabsf(v3)));
        #pragma unroll
        for (int d = 1; d < 64; d <<= 1) am = fmaxf(am, __shfl_xor(am, d));
        const float inv = am > 0.f ? 127.f / am : 0.f;
        const unsigned int b0 = (unsigned int)__float2int_rn(v0 * inv) & 255u;
        const unsigned int b1 = (unsigned int)__float2int_rn(v1 * inv) & 255u;
        const unsigned int b2 = (unsigned int)__float2int_rn(v2 * inv) & 255u;
        const unsigned int b3 = (unsigned int)__float2int_rn(v3 * inv) & 255u;
        sQ1[wv][lane] = b0 | (b1 << 8) | (b2 << 16) | (b3 << 24);
        if (lane == 0) sS[wv] = (am / 127.f) * 0.0625f;
    }
    __syncthreads();

    // A fragments from LDS: lane = pixel (lane&15), chans (lane>>4)*16 + 64*kk
    // u32 index = (lane>>4)*4 + 16*kk  (16B-aligned within padded row)
    const unsigned int* qrow = sQ1[lane & 15];
    const int qi = (lane >> 4) << 2;
    const int4v A0 = *reinterpret_cast<const int4v*>(qrow + qi);
    const int4v A1 = *reinterpret_cast<const int4v*>(qrow + qi + 16);
    const int4v A2 = *reinterpret_cast<const int4v*>(qrow + qi + 32);
    const int4v A3 = *reinterpret_cast<const int4v*>(qrow + qi + 48);

    #pragma unroll
    for (int w = 0; w < 4; ++w) {
        const int Wl = W0 >> w;
        const int Hl = H0 >> w;
        const int texoff = (w == 0) ? 0 : (w == 1) ? 8192 : (w == 2) ? 10240 : 10752;
        const signed char* lvl = pyrQ + ((size_t)texoff << 8);
        const float* s2l = s2 + texoff;

        int minX = 1 << 30, maxX = -(1 << 30), minY = 1 << 30, maxY = -(1 << 30);
        #pragma unroll
        for (int p = 0; p < 16; ++p) {
            const int x0 = sX0[w][p], y0 = sY0[w][p];
            minX = min(minX, x0); maxX = max(maxX, x0);
            minY = min(minY, y0); maxY = max(maxY, y0);
        }
        const int xlo = max(minX - 4, 0), xhi = min(maxX + 5, Wl - 1);
        const int ylo = max(minY - 4, 0), yhi = min(maxY + 5, Hl - 1);
        if (xlo > xhi || ylo > yhi) continue;
        const int span  = xhi - xlo + 1;
        const int cpr   = (span + 15) >> 4;
        const int items = (yhi - ylo + 1) * cpr;
        const unsigned mgc = (16777215u / (unsigned)cpr) + 1u;  // ceil(2^24/cpr)

        for (int it = wv; it < items; it += 16) {
            const int rowi = (int)(((unsigned long long)(unsigned)it * mgc) >> 24);
            const int gy   = ylo + rowi;
            const int t0   = xlo + (it - rowi * cpr) * 16;
            const int gxl  = t0 + (lane & 15);
            const int gxc  = min(gxl, xhi);
            const signed char* bp = lvl + (((size_t)(gy * Wl + gxc)) << 8) + ((lane >> 4) << 4);
            int4v acc = {0, 0, 0, 0};
            acc = mfma_i8_16x16x64(A0, *reinterpret_cast<const int4v*>(bp),       acc);
            acc = mfma_i8_16x16x64(A1, *reinterpret_cast<const int4v*>(bp + 64),  acc);
            acc = mfma_i8_16x16x64(A2, *reinterpret_cast<const int4v*>(bp + 128), acc);
            acc = mfma_i8_16x16x64(A3, *reinterpret_cast<const int4v*>(bp + 192), acc);
            const float s2v = s2l[gy * Wl + gxc];
            const bool xok = (gxl <= xhi);
            #pragma unroll
            for (int r = 0; r < 4; ++r) {
                const int px = ((lane >> 4) << 2) + r;
                const int j = gy - sY0[w][px] + 4;
                const int i = gxl - sX0[w][px] + 4;
                if (xok && (unsigned)j < 10u && (unsigned)i < 10u)
                    sG[px][w][j * 10 + i] = (float)acc[r] * s2v;
            }
        }
    }
    __syncthreads();

    const int cpx = tid & 15;
    const float s1v = sS[cpx];
    for (int o = tid >> 4; o < 324; o += 64) {
        const int lev = (o * 811) >> 16;
        const int k   = o - lev * 81;
        const int a   = (k * 57) >> 9;
        const int bb  = k - a * 9;
        const float fx = sF[cpx][lev][0], fy = sF[cpx][lev][1];
        const float wx0 = 1.0f - fx, wy0 = 1.0f - fy;
        const float* G = sG[cpx][lev];
        const float v = wy0 * (wx0 * G[bb * 10 + a]       + fx * G[bb * 10 + a + 1])
                      + fy  * (wx0 * G[(bb + 1) * 10 + a] + fx * G[(bb + 1) * 10 + a + 1]);
        out[(size_t)o * HW + m0 + cpx] = v * s1v;
    }
}

extern "C" void kernel_launch(void* const* d_in, const int* in_sizes, int n_in,
                              void* d_out, int out_size, void* d_ws, size_t ws_size,
                              hipStream_t stream) {
    const float* fmap1  = (const float*)d_in[0];
    const float* fmap2  = (const float*)d_in[1];
    const float* coords = (const float*)d_in[2];
    float* out = (float*)d_out;

    char* ws = (char*)d_ws;
    float* s2         = (float*)ws;                         // 43,520
    signed char* pyrQ = (signed char*)(ws + 65536);         // 2,785,280
    _Float16* p0      = (_Float16*)(ws + 2916352);          // 4,194,304
    _Float16* p1      = (_Float16*)(ws + 7110656);          // 1,048,576
    _Float16* p2      = (_Float16*)(ws + 8159232);          // 262,144

    k_tq_f2<<<HW / 32, 256, 0, stream>>>(fmap2, p0, pyrQ, s2);
    k_pool_q<<<32 * 64, 256, 0, stream>>>(p0, p1, pyrQ, s2, 64, 128, 8192, 1);
    k_pool_q<<<16 * 32, 256, 0, stream>>>(p1, p2, pyrQ, s2, 32, 64, 10240, 1);
    k_pool_q<<<8 * 16, 256, 0, stream>>>(p2, (_Float16*)0, pyrQ, s2, 16, 32, 10752, 0);
    k_sample_mfma<<<HW / 16, 1024, 0, stream>>>(fmap1, pyrQ, s2, coords, out);
}